// Round 8
// baseline (380.916 us; speedup 1.0000x reference)
//
#include <hip/hip_runtime.h>
#include <hip/hip_bf16.h>

// ---------------------------------------------------------------------------
// CausalSelfAttention (B=2,T=2048,C=2048,H=16,KVH=4,HD=128) on gfx950.
// Pipeline: cvt(x) ; transpose+cvt(wq,wk,wv,wo) ; 8-phase GEMM->qkv ;
//           rope+rms ; flash-attn (swapped-QK^T) ; 8-phase GEMM->out.
// ---------------------------------------------------------------------------

using bf16 = __bf16;
typedef __bf16 bf16x8 __attribute__((ext_vector_type(8)));
typedef __bf16 bf16x4 __attribute__((ext_vector_type(4)));
typedef float  f32x4  __attribute__((ext_vector_type(4)));

__device__ __forceinline__ void gload_lds16(const void* g, void* l) {
  __builtin_amdgcn_global_load_lds(
      (const __attribute__((address_space(1))) unsigned int*)g,
      (__attribute__((address_space(3))) unsigned int*)l, 16, 0, 0);
}

__device__ __forceinline__ unsigned pack2(float a, float b) {
  unsigned short ua = __builtin_bit_cast(unsigned short, (bf16)a);
  unsigned short ub = __builtin_bit_cast(unsigned short, (bf16)b);
  return ((unsigned)ub << 16) | ua;
}

#define SBAR() __builtin_amdgcn_s_barrier()
#define WAIT_LGKM0() do { asm volatile("s_waitcnt lgkmcnt(0)" ::: "memory"); \
                          __builtin_amdgcn_sched_barrier(0); } while (0)
#define WAIT_VM0() asm volatile("s_waitcnt vmcnt(0)" ::: "memory")

// --------------------------- elementwise convert ---------------------------
__global__ __launch_bounds__(256) void k_cvt_bf16(const float* __restrict__ src,
                                                  bf16* __restrict__ dst) {
  const int i = blockIdx.x * 256 + threadIdx.x;
  f32x4 v = ((const f32x4*)src)[i];
  bf16x4 o;
  o[0] = (bf16)v[0]; o[1] = (bf16)v[1]; o[2] = (bf16)v[2]; o[3] = (bf16)v[3];
  ((bf16x4*)dst)[i] = o;
}

// ----------------------- transpose + convert (weights) ---------------------
__global__ __launch_bounds__(256) void k_transpose_cvt(const float* __restrict__ src,
                                                       bf16* __restrict__ dst,
                                                       int R, int C) {
  __shared__ float tile[32][33];
  const int c0 = blockIdx.x * 32, r0 = blockIdx.y * 32;
  const int tx = threadIdx.x & 31, ty = threadIdx.x >> 5;
#pragma unroll
  for (int j = 0; j < 32; j += 8)
    tile[ty + j][tx] = src[(size_t)(r0 + ty + j) * C + c0 + tx];
  __syncthreads();
#pragma unroll
  for (int j = 0; j < 32; j += 8)
    dst[(size_t)(c0 + ty + j) * R + r0 + tx] = (bf16)tile[tx][ty + j];
}

// ----------------------- 8-phase GEMM (T2+T3+T4+T5) ------------------------
// C(M,Ntot) = A(M,K) @ B^T, B as (N,K) k-major.  512 thr / 8 waves (2x4),
// BK=64, BN=256, BM in {256,128}.  Per K-tile: 4 phases, each
// {stage-issue || ds_read subtile -> s_barrier -> lgkmcnt(0) -> MFMA -> s_barrier},
// single vmcnt(0) per tile after the last phase's MFMA (counted, never per-phase).
// B-frags read once per tile and held in registers.  chunk^(row&7) LDS swizzle
// applied source-side (pre-swizzled global col) and read-side (same XOR).
template <int BM, bool OUT_BF16>
__global__ __launch_bounds__(512, 2) void k_gemm8(
    const bf16* __restrict__ A,
    const bf16* __restrict__ B0, const bf16* __restrict__ B1,
    const bf16* __restrict__ B2, int nb1, int nb2,
    void* __restrict__ Cout, int K, int Ntot) {
  constexpr int MR  = BM / 32;   // row frags per wave (8 or 4)
  constexpr int RPP = MR / 4;    // row frags per phase (2 or 1)
  constexpr int ACH = BM / 64;   // A staging chunks (4 or 2)
  __shared__ __align__(16) bf16 As[2][BM * 64];
  __shared__ __align__(16) bf16 Bs[2][256 * 64];
  const int nb = blockIdx.x, mb = blockIdx.y;
  const bf16* Bt; int nloc;
  if (nb < nb1)      { Bt = B0; nloc = nb; }
  else if (nb < nb2) { Bt = B1; nloc = nb - nb1; }
  else               { Bt = B2; nloc = nb - nb2; }
  const int tid = threadIdx.x;
  const int w = tid >> 6, lane = tid & 63;
  const int wm = w >> 2, wn = w & 3;          // 2 x 4 wave grid
  const int l16 = lane & 15, lq = lane >> 4;
  const int r8 = lane >> 3, c8 = lane & 7;    // staging: 8 rows x 8 chunks
  const bf16* Ag = A  + (size_t)mb * BM * K;
  const bf16* Bg = Bt + (size_t)nloc * 256 * K;

  f32x4 acc[MR][4] = {};

  auto stageA = [&](int bn, int k0, int ch) {
    const int r = ch * 64 + w * 8 + r8;
    gload_lds16(Ag + (size_t)r * K + k0 + ((c8 ^ (r & 7)) << 3),
                &As[bn][(ch * 64 + w * 8) * 64]);
  };
  auto stageB = [&](int bn, int k0, int ch) {
    const int r = ch * 64 + w * 8 + r8;
    gload_lds16(Bg + (size_t)r * K + k0 + ((c8 ^ (r & 7)) << 3),
                &Bs[bn][(ch * 64 + w * 8) * 64]);
  };

  // prologue: stage tile 0 fully
#pragma unroll
  for (int ch = 0; ch < ACH; ++ch) stageA(0, 0, ch);
#pragma unroll
  for (int ch = 0; ch < 4; ++ch) stageB(0, 0, ch);
  WAIT_VM0();
  SBAR();

  const int NT = K / 64;
  bf16x8 bfr[4][2];                        // B-frags, live across a K-tile
  for (int t = 0; t < NT; ++t) {
    const int buf = t & 1;
    const int k0n = (t + 1) * 64;
    const bool pf = (t + 1 < NT);
#pragma unroll
    for (int p = 0; p < 4; ++p) {
      // ---- stage issues for tile t+1 (front-loaded: chunk 3 still gets
      //      >=1 phase + phase-3 compute to land before the tile-end vmcnt) ----
      if (pf) {
        if (p == 0) {
          stageB(buf ^ 1, k0n, 0); stageB(buf ^ 1, k0n, 1);
          stageA(buf ^ 1, k0n, 0);
          if (ACH > 1) stageA(buf ^ 1, k0n, 1);
        } else if (p == 1) {
          stageB(buf ^ 1, k0n, 2);
          if (ACH > 2) stageA(buf ^ 1, k0n, 2);
        } else if (p == 2) {
          stageB(buf ^ 1, k0n, 3);
          if (ACH > 3) stageA(buf ^ 1, k0n, 3);
        }
      }
      // ---- ds_read this phase's fragments ----
      if (p == 0) {
#pragma unroll
        for (int j = 0; j < 4; ++j)
#pragma unroll
          for (int kc = 0; kc < 2; ++kc) {
            const int rb = wn * 64 + j * 16 + l16;
            bfr[j][kc] = *(const bf16x8*)((const char*)&Bs[buf][0] +
                          rb * 128 + ((kc * 64 + lq * 16) ^ ((rb & 7) << 4)));
          }
      }
      bf16x8 af[RPP][2];
#pragma unroll
      for (int ii = 0; ii < RPP; ++ii)
#pragma unroll
        for (int kc = 0; kc < 2; ++kc) {
          const int ra = wm * (BM / 2) + (p * RPP + ii) * 16 + l16;
          af[ii][kc] = *(const bf16x8*)((const char*)&As[buf][0] +
                        ra * 128 + ((kc * 64 + lq * 16) ^ ((ra & 7) << 4)));
        }
      SBAR();
      WAIT_LGKM0();
      __builtin_amdgcn_s_setprio(1);
#pragma unroll
      for (int kc = 0; kc < 2; ++kc)
#pragma unroll
        for (int ii = 0; ii < RPP; ++ii)
#pragma unroll
          for (int j = 0; j < 4; ++j)
            acc[p * RPP + ii][j] = __builtin_amdgcn_mfma_f32_16x16x32_bf16(
                af[ii][kc], bfr[j][kc], acc[p * RPP + ii][j], 0, 0, 0);
      __builtin_amdgcn_s_setprio(0);
      if (p == 3 && pf) WAIT_VM0();   // tile t+1 landed; counted once per tile
      SBAR();
    }
  }

  // epilogue: D row = (lane>>4)*4 + reg, col = lane&15 (m89-verified mapping)
#pragma unroll
  for (int i = 0; i < MR; ++i)
#pragma unroll
    for (int j = 0; j < 4; ++j)
#pragma unroll
      for (int e = 0; e < 4; ++e) {
        const size_t row = (size_t)mb * BM + wm * (BM / 2) + i * 16 + lq * 4 + e;
        const size_t col = (size_t)nb * 256 + wn * 64 + j * 16 + l16;
        if (OUT_BF16) ((bf16*)Cout)[row * Ntot + col] = (bf16)acc[i][j][e];
        else          ((float*)Cout)[row * Ntot + col] = acc[i][j][e];
      }
}

// ----------------------------- RoPE + RMSnorm ------------------------------
__global__ __launch_bounds__(256) void k_rope(
    const bf16* __restrict__ qkv, const float* __restrict__ cosb,
    const float* __restrict__ sinb, bf16* __restrict__ q_r,
    bf16* __restrict__ k_r, bf16* __restrict__ v_t) {
  const int wid  = blockIdx.x * 4 + (threadIdx.x >> 6);
  const int lane = threadIdx.x & 63;
  const int head = wid % 24;
  const int bt   = wid / 24;
  const int b = bt >> 11, t = bt & 2047;
  const bf16* base = qkv + (size_t)bt * 3072;
  if (head >= 20) {
    const int kv = head - 20;
    const bf16 v1 = base[2560 + kv * 128 + lane];
    const bf16 v2 = base[2560 + kv * 128 + 64 + lane];
    const size_t o = (size_t)((b * 4 + kv) * 128);
    v_t[(o + lane) * 2048 + t]      = v1;
    v_t[(o + 64 + lane) * 2048 + t] = v2;
    return;
  }
  const int col = (head < 16) ? head * 128 : 2048 + (head - 16) * 128;
  const float x1 = (float)base[col + lane];
  const float x2 = (float)base[col + 64 + lane];
  const float c = cosb[t * 64 + lane], s = sinb[t * 64 + lane];
  const float o1 = x1 * c + x2 * s;
  const float o2 = x2 * c - x1 * s;
  float ss = o1 * o1 + o2 * o2;
#pragma unroll
  for (int off = 32; off >= 1; off >>= 1) ss += __shfl_xor(ss, off);
  float r = rsqrtf(ss * (1.0f / 128.0f) + 1e-5f);
  if (head < 16) {
    r *= 0.08838834764831845f;
    const size_t o = ((size_t)(b * 16 + head) * 2048 + t) * 128;
    q_r[o + lane]      = (bf16)(o1 * r);
    q_r[o + 64 + lane] = (bf16)(o2 * r);
  } else {
    const int kv = head - 16;
    const size_t o = ((size_t)(b * 4 + kv) * 2048 + t) * 128;
    k_r[o + lane]      = (bf16)(o1 * r);
    k_r[o + 64 + lane] = (bf16)(o2 * r);
  }
}

// ------------------------------ flash attention ----------------------------
// (unchanged from Round-1-verified version)
__global__ __launch_bounds__(256, 2) void k_attn(
    const bf16* __restrict__ q_r, const bf16* __restrict__ k_r,
    const bf16* __restrict__ v_t, bf16* __restrict__ y) {
  __shared__ __align__(16) bf16 Ks[2][64 * 128];   // [buf][kv][d]
  __shared__ __align__(16) bf16 Vt[2][128 * 64];   // [buf][d][kv]
  const int blkid = blockIdx.x;
  const int bh = (blkid & 7) * 4 + ((blkid >> 3) & 3);
  const int g  = blkid >> 5;
  const int qb = (blkid < 256) ? (15 - g) : (g - 8);
  const int b = bh >> 4, h = bh & 15;
  const int bkv = b * 4 + (h >> 2);
  const int tid = threadIdx.x, w = tid >> 6, lane = tid & 63;
  const int l16 = lane & 15, lq = lane >> 4;
  const int swz = (l16 & 7) << 4;
  const int q0 = qb * 128, t0A = q0 + w * 32;
  const int nt = 2 * qb + 2;
  const bf16* kb = k_r + (size_t)bkv * (2048 * 128);
  const bf16* vb = v_t + (size_t)bkv * (128 * 2048);

  bf16x8 qfA[4], qfB[4];
  const bf16* qbase = q_r + ((size_t)bh * 2048 + t0A + l16) * 128;
#pragma unroll
  for (int kc = 0; kc < 4; ++kc) {
    qfA[kc] = *(const bf16x8*)(qbase + 32 * kc + 8 * lq);
    qfB[kc] = *(const bf16x8*)(qbase + 16 * 128 + 32 * kc + 8 * lq);
  }

  f32x4 accA[8] = {}, accB[8] = {};
  float mA = -1e29f, mB = -1e29f, lA = 0.f, lB = 0.f;

  auto stage = [&](int buf, int s0n) {
#pragma unroll
    for (int it = 0; it < 4; ++it) {
      const int rK = w * 16 + it * 4 + (lane >> 4);
      gload_lds16(kb + (size_t)(s0n + rK) * 128 + (((lane & 15) ^ (rK & 7)) << 3),
                  &Ks[buf][(w * 16 + it * 4) * 128]);
      const int rV = w * 32 + it * 8 + (lane >> 3);
      gload_lds16(vb + (size_t)rV * 2048 + s0n + (((lane & 7) ^ (rV & 7)) << 3),
                  &Vt[buf][(w * 32 + it * 8) * 64]);
    }
  };

  stage(0, 0);
  asm volatile("s_waitcnt vmcnt(0)" ::: "memory");
  __syncthreads();

  for (int t = 0; t < nt; ++t) {
    if (t + 1 < nt) stage((t + 1) & 1, (t + 1) * 64);
    const int s0 = t * 64;
    const int buf = t & 1;
    if (s0 <= t0A + 31) {
      f32x4 stA[4] = {}, stB[4] = {};
#pragma unroll
      for (int kc = 0; kc < 4; ++kc)
#pragma unroll
        for (int n = 0; n < 4; ++n) {
          const int rk = 16 * n + l16;
          const bf16x8 kf = *(const bf16x8*)((const char*)&Ks[buf][0] +
                             rk * 256 + ((64 * kc + 16 * lq) ^ swz));
          stA[n] = __builtin_amdgcn_mfma_f32_16x16x32_bf16(kf, qfA[kc], stA[n], 0, 0, 0);
          stB[n] = __builtin_amdgcn_mfma_f32_16x16x32_bf16(kf, qfB[kc], stB[n], 0, 0, 0);
        }
      const int qgA = t0A + l16, qgB = qgA + 16;
      if (s0 + 63 > t0A) {
#pragma unroll
        for (int n = 0; n < 4; ++n)
#pragma unroll
          for (int e = 0; e < 4; ++e) {
            const int kvg = s0 + 16 * n + 4 * lq + e;
            if (kvg > qgA) stA[n][e] = -1e30f;
            if (kvg > qgB) stB[n][e] = -1e30f;
          }
      }
      float mxA = -1e30f, mxB = -1e30f;
#pragma unroll
      for (int n = 0; n < 4; ++n)
#pragma unroll
        for (int e = 0; e < 4; ++e) {
          mxA = fmaxf(mxA, stA[n][e]);
          mxB = fmaxf(mxB, stB[n][e]);
        }
      mxA = fmaxf(mxA, __shfl_xor(mxA, 16)); mxA = fmaxf(mxA, __shfl_xor(mxA, 32));
      mxB = fmaxf(mxB, __shfl_xor(mxB, 16)); mxB = fmaxf(mxB, __shfl_xor(mxB, 32));
      const bool small = (mxA <= mA + 8.f) && (mxB <= mB + 8.f);
      if (!__all(small)) {
        const float mnA = fmaxf(mA, mxA), mnB = fmaxf(mB, mxB);
        const float scA = __expf(mA - mnA), scB = __expf(mB - mnB);
        mA = mnA; mB = mnB; lA *= scA; lB *= scB;
#pragma unroll
        for (int d2 = 0; d2 < 8; ++d2) { accA[d2] *= scA; accB[d2] *= scB; }
      }
      float rsA = 0.f, rsB = 0.f;
#pragma unroll
      for (int n = 0; n < 4; ++n)
#pragma unroll
        for (int e = 0; e < 4; ++e) {
          stA[n][e] = __expf(stA[n][e] - mA); rsA += stA[n][e];
          stB[n][e] = __expf(stB[n][e] - mB); rsB += stB[n][e];
        }
      rsA += __shfl_xor(rsA, 16); rsA += __shfl_xor(rsA, 32); lA += rsA;
      rsB += __shfl_xor(rsB, 16); rsB += __shfl_xor(rsB, 32); lB += rsB;
      unsigned pA2[8], pB2[8];
#pragma unroll
      for (int n = 0; n < 4; ++n) {
        pA2[n * 2 + 0] = pack2(stA[n][0], stA[n][1]);
        pA2[n * 2 + 1] = pack2(stA[n][2], stA[n][3]);
        pB2[n * 2 + 0] = pack2(stB[n][0], stB[n][1]);
        pB2[n * 2 + 1] = pack2(stB[n][2], stB[n][3]);
      }
      const int src0 = l16 | ((((lq & 1) << 1) | 0) << 4);
      const int src1 = l16 | ((((lq & 1) << 1) | 1) << 4);
      const bool selhi = (lq & 2);
#pragma unroll
      for (int c = 0; c < 2; ++c) {
        union { unsigned u[4]; bf16x8 v; } wA, wB;
        {
          unsigned a0 = __shfl((int)pA2[(2*c)*2+0], src0), b0 = __shfl((int)pA2[(2*c+1)*2+0], src0);
          unsigned a1 = __shfl((int)pA2[(2*c)*2+1], src0), b1 = __shfl((int)pA2[(2*c+1)*2+1], src0);
          unsigned a2 = __shfl((int)pA2[(2*c)*2+0], src1), b2 = __shfl((int)pA2[(2*c+1)*2+0], src1);
          unsigned a3 = __shfl((int)pA2[(2*c)*2+1], src1), b3 = __shfl((int)pA2[(2*c+1)*2+1], src1);
          wA.u[0] = selhi ? b0 : a0; wA.u[1] = selhi ? b1 : a1;
          wA.u[2] = selhi ? b2 : a2; wA.u[3] = selhi ? b3 : a3;
        }
        {
          unsigned a0 = __shfl((int)pB2[(2*c)*2+0], src0), b0 = __shfl((int)pB2[(2*c+1)*2+0], src0);
          unsigned a1 = __shfl((int)pB2[(2*c)*2+1], src0), b1 = __shfl((int)pB2[(2*c+1)*2+1], src0);
          unsigned a2 = __shfl((int)pB2[(2*c)*2+0], src1), b2 = __shfl((int)pB2[(2*c+1)*2+0], src1);
          unsigned a3 = __shfl((int)pB2[(2*c)*2+1], src1), b3 = __shfl((int)pB2[(2*c+1)*2+1], src1);
          wB.u[0] = selhi ? b0 : a0; wB.u[1] = selhi ? b1 : a1;
          wB.u[2] = selhi ? b2 : a2; wB.u[3] = selhi ? b3 : a3;
        }
#pragma unroll
        for (int dblk = 0; dblk < 8; ++dblk) {
          const int rv = 16 * dblk + l16;
          const bf16x8 vf = *(const bf16x8*)((const char*)&Vt[buf][0] +
                             rv * 128 + ((64 * c + 16 * lq) ^ swz));
          accA[dblk] = __builtin_amdgcn_mfma_f32_16x16x32_bf16(vf, wA.v, accA[dblk], 0, 0, 0);
          accB[dblk] = __builtin_amdgcn_mfma_f32_16x16x32_bf16(vf, wB.v, accB[dblk], 0, 0, 0);
        }
      }
    }
    asm volatile("s_waitcnt vmcnt(0)" ::: "memory");
    __syncthreads();
  }

  const float invA = 1.f / lA, invB = 1.f / lB;
  bf16* yA = y + (((size_t)b * 2048 + t0A + l16) * 16 + h) * 128;
  bf16* yB = yA + (size_t)16 * 2048;
#pragma unroll
  for (int dblk = 0; dblk < 8; ++dblk) {
    unsigned loA = pack2(accA[dblk][0] * invA, accA[dblk][1] * invA);
    unsigned hiA = pack2(accA[dblk][2] * invA, accA[dblk][3] * invA);
    *(uint2*)(yA + 16 * dblk + 4 * lq) = make_uint2(loA, hiA);
    unsigned loB = pack2(accB[dblk][0] * invB, accB[dblk][1] * invB);
    unsigned hiB = pack2(accB[dblk][2] * invB, accB[dblk][3] * invB);
    *(uint2*)(yB + 16 * dblk + 4 * lq) = make_uint2(loB, hiB);
  }
}

// --------------------------------- launch ----------------------------------
extern "C" void kernel_launch(void* const* d_in, const int* in_sizes, int n_in,
                              void* d_out, int out_size, void* d_ws, size_t ws_size,
                              hipStream_t stream) {
  const float* x    = (const float*)d_in[0];
  const float* cosb = (const float*)d_in[1];
  const float* sinb = (const float*)d_in[2];
  const float* wq   = (const float*)d_in[3];
  const float* wk   = (const float*)d_in[4];
  const float* wv   = (const float*)d_in[5];
  const float* wo   = (const float*)d_in[6];
  float* out = (float*)d_out;

  char* ws = (char*)d_ws;
  size_t off = 0;
  auto alloc = [&](size_t bytes) {
    char* p = ws + off; off += (bytes + 255) & ~(size_t)255; return p;
  };
  bf16* xb  = (bf16*)alloc(4096ull * 2048 * 2);
  bf16* wqT = (bf16*)alloc(2048ull * 2048 * 2);
  bf16* wkT = (bf16*)alloc(512ull  * 2048 * 2);
  bf16* wvT = (bf16*)alloc(512ull  * 2048 * 2);
  bf16* woT = (bf16*)alloc(2048ull * 2048 * 2);
  bf16* qkv = (bf16*)alloc(4096ull * 3072 * 2);
  bf16* q_r = (bf16*)alloc(4096ull * 2048 * 2);
  bf16* k_r = (bf16*)alloc(4096ull * 512  * 2);
  bf16* v_t = (bf16*)alloc(4096ull * 512  * 2);
  bf16* y   = xb;                                  // xb dead after gemm_qkv

  k_cvt_bf16<<<(4096 * 2048 / 4) / 256, 256, 0, stream>>>(x, xb);
  k_transpose_cvt<<<dim3(64, 64), 256, 0, stream>>>(wq, wqT, 2048, 2048);
  k_transpose_cvt<<<dim3(16, 64), 256, 0, stream>>>(wk, wkT, 2048, 512);
  k_transpose_cvt<<<dim3(16, 64), 256, 0, stream>>>(wv, wvT, 2048, 512);
  k_transpose_cvt<<<dim3(64, 64), 256, 0, stream>>>(wo, woT, 2048, 2048);
  // qkv = x @ [wq|wk|wv]: BN=256 col-blocks 0-7=wq, 8-9=wk, 10-11=wv
  k_gemm8<256, true><<<dim3(12, 16), 512, 0, stream>>>(xb, wqT, wkT, wvT, 8, 10,
                                                       qkv, 2048, 3072);
  k_rope<<<24576, 256, 0, stream>>>(qkv, cosb, sinb, q_r, k_r, v_t);
  k_attn<<<512, 256, 0, stream>>>(q_r, k_r, v_t, y);
  // out = y @ wo : BM=128 x BN=256 -> grid 8x32 = 256 blocks (1 full CU round)
  k_gemm8<128, false><<<dim3(8, 32), 512, 0, stream>>>(y, woT, woT, woT, 100, 200,
                                                       out, 2048, 2048);
}

// Round 9
// 364.589 us; speedup vs baseline: 1.0448x; 1.0448x over previous
//
#include <hip/hip_runtime.h>
#include <hip/hip_bf16.h>

// ---------------------------------------------------------------------------
// CausalSelfAttention (B=2,T=2048,C=2048,H=16,KVH=4,HD=128) on gfx950.
// Pipeline: cvt(x) ; transpose+cvt(w*) ; ring-GEMM->qkv ; rope+rms ;
//           flash-attn (swapped-QK^T) ; ring-GEMM->out.
// GEMM: BK=32, 4-deep LDS ring, counted vmcnt (never drain in steady state).
// ---------------------------------------------------------------------------

using bf16 = __bf16;
typedef __bf16 bf16x8 __attribute__((ext_vector_type(8)));
typedef __bf16 bf16x4 __attribute__((ext_vector_type(4)));
typedef float  f32x4  __attribute__((ext_vector_type(4)));

__device__ __forceinline__ void gload_lds16(const void* g, void* l) {
  __builtin_amdgcn_global_load_lds(
      (const __attribute__((address_space(1))) unsigned int*)g,
      (__attribute__((address_space(3))) unsigned int*)l, 16, 0, 0);
}

__device__ __forceinline__ unsigned pack2(float a, float b) {
  unsigned short ua = __builtin_bit_cast(unsigned short, (bf16)a);
  unsigned short ub = __builtin_bit_cast(unsigned short, (bf16)b);
  return ((unsigned)ub << 16) | ua;
}

#define SBAR() do { __builtin_amdgcn_s_barrier(); \
                    __builtin_amdgcn_sched_barrier(0); } while (0)
#define VMCNT(n) asm volatile("s_waitcnt vmcnt(" #n ")" ::: "memory")

// --------------------------- elementwise convert ---------------------------
__global__ __launch_bounds__(256) void k_cvt_bf16(const float* __restrict__ src,
                                                  bf16* __restrict__ dst) {
  const int i = blockIdx.x * 256 + threadIdx.x;
  f32x4 v = ((const f32x4*)src)[i];
  bf16x4 o;
  o[0] = (bf16)v[0]; o[1] = (bf16)v[1]; o[2] = (bf16)v[2]; o[3] = (bf16)v[3];
  ((bf16x4*)dst)[i] = o;
}

// ----------------------- transpose + convert (weights) ---------------------
__global__ __launch_bounds__(256) void k_transpose_cvt(const float* __restrict__ src,
                                                       bf16* __restrict__ dst,
                                                       int R, int C) {
  __shared__ float tile[32][33];
  const int c0 = blockIdx.x * 32, r0 = blockIdx.y * 32;
  const int tx = threadIdx.x & 31, ty = threadIdx.x >> 5;
#pragma unroll
  for (int j = 0; j < 32; j += 8)
    tile[ty + j][tx] = src[(size_t)(r0 + ty + j) * C + c0 + tx];
  __syncthreads();
#pragma unroll
  for (int j = 0; j < 32; j += 8)
    dst[(size_t)(c0 + ty + j) * R + r0 + tx] = (bf16)tile[tx][ty + j];
}

// -------------------- ring-buffer GEMM (counted vmcnt, T4) -----------------
// C(M,Ntot) = A(M,K) @ B^T, B as (N,K) k-major.  512 thr / 8 waves (2M x 4N),
// BN=256, BK=32, 4 LDS tile-buffers.  Body t: stage tile t+3, wait vmcnt(3L)
// (L = loads/tile/wave) so 3 tiles stay in flight, barrier, ds_read frags,
// MFMA under setprio, barrier.  Tail peels to vmcnt(2L/L/0).
// LDS swizzle: chunk ^= (row>>1)&3 (2-way = free), source- and read-side.
template <int BM, bool OUT_BF16>
__global__ __launch_bounds__(512, 1) void k_gemm32(
    const bf16* __restrict__ A,
    const bf16* __restrict__ B0, const bf16* __restrict__ B1,
    const bf16* __restrict__ B2, int nb1, int nb2,
    void* __restrict__ Cout, int K, int Ntot) {
  constexpr int MR  = BM / 32;   // M frags per wave (8 or 4)
  constexpr int ACH = BM / 128;  // A staging instrs per tile (2 or 1)
  __shared__ __align__(16) bf16 As[4][BM * 32];
  __shared__ __align__(16) bf16 Bs[4][256 * 32];
  const int nb = blockIdx.x, mb = blockIdx.y;
  const bf16* Bt; int nloc;
  if (nb < nb1)      { Bt = B0; nloc = nb; }
  else if (nb < nb2) { Bt = B1; nloc = nb - nb1; }
  else               { Bt = B2; nloc = nb - nb2; }
  const int tid = threadIdx.x;
  const int w = tid >> 6, lane = tid & 63;
  const int wm = w >> 2, wn = w & 3;          // 2 x 4 wave grid
  const int l16 = lane & 15, lq = lane >> 4;
  const int sr4 = lane >> 2, sc4 = lane & 3;  // staging: 16 rows x 4 chunks/wave
  const bf16* Ag = A  + (size_t)mb * BM * K;
  const bf16* Bg = Bt + (size_t)nloc * 256 * K;

  f32x4 acc[MR][4] = {};

  auto stage = [&](int t) {
    const int buf = t & 3;
    const int k0 = t * 32;
#pragma unroll
    for (int i = 0; i < 2; ++i) {             // B: 2 x 128 rows
      const int r = i * 128 + w * 16 + sr4;
      const int cg = sc4 ^ ((r >> 1) & 3);
      gload_lds16(Bg + (size_t)r * K + k0 + cg * 8,
                  &Bs[buf][(i * 128 + w * 16) * 32]);
    }
#pragma unroll
    for (int i = 0; i < ACH; ++i) {           // A: ACH x 128 rows
      const int r = i * 128 + w * 16 + sr4;
      const int cg = sc4 ^ ((r >> 1) & 3);
      gload_lds16(Ag + (size_t)r * K + k0 + cg * 8,
                  &As[buf][(i * 128 + w * 16) * 32]);
    }
  };

  const int NT = K / 32;
  // prologue: 3 tiles in flight, wait for tile 0 (2L outstanding afterwards)
  stage(0); stage(1); stage(2);
  if (BM == 256) VMCNT(8); else VMCNT(6);
  SBAR();

  for (int t = 0; t < NT; ++t) {
    const int buf = t & 3;
    if (t + 3 < NT) stage(t + 3);             // ring slot (t+3)&3: safe, last
                                              // read at body t-1 (barrier'd)
    const int rem = NT - 1 - t;               // staged tiles beyond t
    if (BM == 256) {
      if (rem >= 3)      VMCNT(12);
      else if (rem == 2) VMCNT(8);
      else if (rem == 1) VMCNT(4);
      else               VMCNT(0);
    } else {
      if (rem >= 3)      VMCNT(9);
      else if (rem == 2) VMCNT(6);
      else if (rem == 1) VMCNT(3);
      else               VMCNT(0);
    }
    SBAR();                                   // tile t visible to all waves
    bf16x8 bfr[4], af[MR];
#pragma unroll
    for (int j = 0; j < 4; ++j) {
      const int rb = wn * 64 + j * 16 + l16;
      bfr[j] = *(const bf16x8*)((const char*)&Bs[buf][0] + rb * 64 +
                                ((lq ^ ((rb >> 1) & 3)) << 4));
    }
#pragma unroll
    for (int i = 0; i < MR; ++i) {
      const int ra = wm * (BM / 2) + i * 16 + l16;
      af[i] = *(const bf16x8*)((const char*)&As[buf][0] + ra * 64 +
                               ((lq ^ ((ra >> 1) & 3)) << 4));
    }
    __builtin_amdgcn_s_setprio(1);
#pragma unroll
    for (int i = 0; i < MR; ++i)
#pragma unroll
      for (int j = 0; j < 4; ++j)
        acc[i][j] = __builtin_amdgcn_mfma_f32_16x16x32_bf16(af[i], bfr[j],
                                                            acc[i][j], 0, 0, 0);
    __builtin_amdgcn_s_setprio(0);
    SBAR();                                   // protect buf t&3 (= (t+4)&3)
  }

  // epilogue: D row = (lane>>4)*4 + reg, col = lane&15 (m89-verified mapping)
#pragma unroll
  for (int i = 0; i < MR; ++i)
#pragma unroll
    for (int j = 0; j < 4; ++j)
#pragma unroll
      for (int e = 0; e < 4; ++e) {
        const size_t row = (size_t)mb * BM + wm * (BM / 2) + i * 16 + lq * 4 + e;
        const size_t col = (size_t)nb * 256 + wn * 64 + j * 16 + l16;
        if (OUT_BF16) ((bf16*)Cout)[row * Ntot + col] = (bf16)acc[i][j][e];
        else          ((float*)Cout)[row * Ntot + col] = acc[i][j][e];
      }
}

// ----------------------------- RoPE + RMSnorm ------------------------------
__global__ __launch_bounds__(256) void k_rope(
    const bf16* __restrict__ qkv, const float* __restrict__ cosb,
    const float* __restrict__ sinb, bf16* __restrict__ q_r,
    bf16* __restrict__ k_r, bf16* __restrict__ v_t) {
  const int wid  = blockIdx.x * 4 + (threadIdx.x >> 6);
  const int lane = threadIdx.x & 63;
  const int head = wid % 24;
  const int bt   = wid / 24;
  const int b = bt >> 11, t = bt & 2047;
  const bf16* base = qkv + (size_t)bt * 3072;
  if (head >= 20) {
    const int kv = head - 20;
    const bf16 v1 = base[2560 + kv * 128 + lane];
    const bf16 v2 = base[2560 + kv * 128 + 64 + lane];
    const size_t o = (size_t)((b * 4 + kv) * 128);
    v_t[(o + lane) * 2048 + t]      = v1;
    v_t[(o + 64 + lane) * 2048 + t] = v2;
    return;
  }
  const int col = (head < 16) ? head * 128 : 2048 + (head - 16) * 128;
  const float x1 = (float)base[col + lane];
  const float x2 = (float)base[col + 64 + lane];
  const float c = cosb[t * 64 + lane], s = sinb[t * 64 + lane];
  const float o1 = x1 * c + x2 * s;
  const float o2 = x2 * c - x1 * s;
  float ss = o1 * o1 + o2 * o2;
#pragma unroll
  for (int off = 32; off >= 1; off >>= 1) ss += __shfl_xor(ss, off);
  float r = rsqrtf(ss * (1.0f / 128.0f) + 1e-5f);
  if (head < 16) {
    r *= 0.08838834764831845f;
    const size_t o = ((size_t)(b * 16 + head) * 2048 + t) * 128;
    q_r[o + lane]      = (bf16)(o1 * r);
    q_r[o + 64 + lane] = (bf16)(o2 * r);
  } else {
    const int kv = head - 16;
    const size_t o = ((size_t)(b * 4 + kv) * 2048 + t) * 128;
    k_r[o + lane]      = (bf16)(o1 * r);
    k_r[o + 64 + lane] = (bf16)(o2 * r);
  }
}

// ------------------------------ flash attention ----------------------------
// (unchanged from Round-7-verified version)
__global__ __launch_bounds__(256, 2) void k_attn(
    const bf16* __restrict__ q_r, const bf16* __restrict__ k_r,
    const bf16* __restrict__ v_t, bf16* __restrict__ y) {
  __shared__ __align__(16) bf16 Ks[2][64 * 128];   // [buf][kv][d]
  __shared__ __align__(16) bf16 Vt[2][128 * 64];   // [buf][d][kv]
  const int blkid = blockIdx.x;
  const int bh = (blkid & 7) * 4 + ((blkid >> 3) & 3);
  const int g  = blkid >> 5;
  const int qb = (blkid < 256) ? (15 - g) : (g - 8);
  const int b = bh >> 4, h = bh & 15;
  const int bkv = b * 4 + (h >> 2);
  const int tid = threadIdx.x, w = tid >> 6, lane = tid & 63;
  const int l16 = lane & 15, lq = lane >> 4;
  const int swz = (l16 & 7) << 4;
  const int q0 = qb * 128, t0A = q0 + w * 32;
  const int nt = 2 * qb + 2;
  const bf16* kb = k_r + (size_t)bkv * (2048 * 128);
  const bf16* vb = v_t + (size_t)bkv * (128 * 2048);

  bf16x8 qfA[4], qfB[4];
  const bf16* qbase = q_r + ((size_t)bh * 2048 + t0A + l16) * 128;
#pragma unroll
  for (int kc = 0; kc < 4; ++kc) {
    qfA[kc] = *(const bf16x8*)(qbase + 32 * kc + 8 * lq);
    qfB[kc] = *(const bf16x8*)(qbase + 16 * 128 + 32 * kc + 8 * lq);
  }

  f32x4 accA[8] = {}, accB[8] = {};
  float mA = -1e29f, mB = -1e29f, lA = 0.f, lB = 0.f;

  auto stage = [&](int buf, int s0n) {
#pragma unroll
    for (int it = 0; it < 4; ++it) {
      const int rK = w * 16 + it * 4 + (lane >> 4);
      gload_lds16(kb + (size_t)(s0n + rK) * 128 + (((lane & 15) ^ (rK & 7)) << 3),
                  &Ks[buf][(w * 16 + it * 4) * 128]);
      const int rV = w * 32 + it * 8 + (lane >> 3);
      gload_lds16(vb + (size_t)rV * 2048 + s0n + (((lane & 7) ^ (rV & 7)) << 3),
                  &Vt[buf][(w * 32 + it * 8) * 64]);
    }
  };

  stage(0, 0);
  asm volatile("s_waitcnt vmcnt(0)" ::: "memory");
  __syncthreads();

  for (int t = 0; t < nt; ++t) {
    if (t + 1 < nt) stage((t + 1) & 1, (t + 1) * 64);
    const int s0 = t * 64;
    const int buf = t & 1;
    if (s0 <= t0A + 31) {
      f32x4 stA[4] = {}, stB[4] = {};
#pragma unroll
      for (int kc = 0; kc < 4; ++kc)
#pragma unroll
        for (int n = 0; n < 4; ++n) {
          const int rk = 16 * n + l16;
          const bf16x8 kf = *(const bf16x8*)((const char*)&Ks[buf][0] +
                             rk * 256 + ((64 * kc + 16 * lq) ^ swz));
          stA[n] = __builtin_amdgcn_mfma_f32_16x16x32_bf16(kf, qfA[kc], stA[n], 0, 0, 0);
          stB[n] = __builtin_amdgcn_mfma_f32_16x16x32_bf16(kf, qfB[kc], stB[n], 0, 0, 0);
        }
      const int qgA = t0A + l16, qgB = qgA + 16;
      if (s0 + 63 > t0A) {
#pragma unroll
        for (int n = 0; n < 4; ++n)
#pragma unroll
          for (int e = 0; e < 4; ++e) {
            const int kvg = s0 + 16 * n + 4 * lq + e;
            if (kvg > qgA) stA[n][e] = -1e30f;
            if (kvg > qgB) stB[n][e] = -1e30f;
          }
      }
      float mxA = -1e30f, mxB = -1e30f;
#pragma unroll
      for (int n = 0; n < 4; ++n)
#pragma unroll
        for (int e = 0; e < 4; ++e) {
          mxA = fmaxf(mxA, stA[n][e]);
          mxB = fmaxf(mxB, stB[n][e]);
        }
      mxA = fmaxf(mxA, __shfl_xor(mxA, 16)); mxA = fmaxf(mxA, __shfl_xor(mxA, 32));
      mxB = fmaxf(mxB, __shfl_xor(mxB, 16)); mxB = fmaxf(mxB, __shfl_xor(mxB, 32));
      const bool small = (mxA <= mA + 8.f) && (mxB <= mB + 8.f);
      if (!__all(small)) {
        const float mnA = fmaxf(mA, mxA), mnB = fmaxf(mB, mxB);
        const float scA = __expf(mA - mnA), scB = __expf(mB - mnB);
        mA = mnA; mB = mnB; lA *= scA; lB *= scB;
#pragma unroll
        for (int d2 = 0; d2 < 8; ++d2) { accA[d2] *= scA; accB[d2] *= scB; }
      }
      float rsA = 0.f, rsB = 0.f;
#pragma unroll
      for (int n = 0; n < 4; ++n)
#pragma unroll
        for (int e = 0; e < 4; ++e) {
          stA[n][e] = __expf(stA[n][e] - mA); rsA += stA[n][e];
          stB[n][e] = __expf(stB[n][e] - mB); rsB += stB[n][e];
        }
      rsA += __shfl_xor(rsA, 16); rsA += __shfl_xor(rsA, 32); lA += rsA;
      rsB += __shfl_xor(rsB, 16); rsB += __shfl_xor(rsB, 32); lB += rsB;
      unsigned pA2[8], pB2[8];
#pragma unroll
      for (int n = 0; n < 4; ++n) {
        pA2[n * 2 + 0] = pack2(stA[n][0], stA[n][1]);
        pA2[n * 2 + 1] = pack2(stA[n][2], stA[n][3]);
        pB2[n * 2 + 0] = pack2(stB[n][0], stB[n][1]);
        pB2[n * 2 + 1] = pack2(stB[n][2], stB[n][3]);
      }
      const int src0 = l16 | ((((lq & 1) << 1) | 0) << 4);
      const int src1 = l16 | ((((lq & 1) << 1) | 1) << 4);
      const bool selhi = (lq & 2);
#pragma unroll
      for (int c = 0; c < 2; ++c) {
        union { unsigned u[4]; bf16x8 v; } wA, wB;
        {
          unsigned a0 = __shfl((int)pA2[(2*c)*2+0], src0), b0 = __shfl((int)pA2[(2*c+1)*2+0], src0);
          unsigned a1 = __shfl((int)pA2[(2*c)*2+1], src0), b1 = __shfl((int)pA2[(2*c+1)*2+1], src0);
          unsigned a2 = __shfl((int)pA2[(2*c)*2+0], src1), b2 = __shfl((int)pA2[(2*c+1)*2+0], src1);
          unsigned a3 = __shfl((int)pA2[(2*c)*2+1], src1), b3 = __shfl((int)pA2[(2*c+1)*2+1], src1);
          wA.u[0] = selhi ? b0 : a0; wA.u[1] = selhi ? b1 : a1;
          wA.u[2] = selhi ? b2 : a2; wA.u[3] = selhi ? b3 : a3;
        }
        {
          unsigned a0 = __shfl((int)pB2[(2*c)*2+0], src0), b0 = __shfl((int)pB2[(2*c+1)*2+0], src0);
          unsigned a1 = __shfl((int)pB2[(2*c)*2+1], src0), b1 = __shfl((int)pB2[(2*c+1)*2+1], src0);
          unsigned a2 = __shfl((int)pB2[(2*c)*2+0], src1), b2 = __shfl((int)pB2[(2*c+1)*2+0], src1);
          unsigned a3 = __shfl((int)pB2[(2*c)*2+1], src1), b3 = __shfl((int)pB2[(2*c+1)*2+1], src1);
          wB.u[0] = selhi ? b0 : a0; wB.u[1] = selhi ? b1 : a1;
          wB.u[2] = selhi ? b2 : a2; wB.u[3] = selhi ? b3 : a3;
        }
#pragma unroll
        for (int dblk = 0; dblk < 8; ++dblk) {
          const int rv = 16 * dblk + l16;
          const bf16x8 vf = *(const bf16x8*)((const char*)&Vt[buf][0] +
                             rv * 128 + ((64 * c + 16 * lq) ^ swz));
          accA[dblk] = __builtin_amdgcn_mfma_f32_16x16x32_bf16(vf, wA.v, accA[dblk], 0, 0, 0);
          accB[dblk] = __builtin_amdgcn_mfma_f32_16x16x32_bf16(vf, wB.v, accB[dblk], 0, 0, 0);
        }
      }
    }
    asm volatile("s_waitcnt vmcnt(0)" ::: "memory");
    __syncthreads();
  }

  const float invA = 1.f / lA, invB = 1.f / lB;
  bf16* yA = y + (((size_t)b * 2048 + t0A + l16) * 16 + h) * 128;
  bf16* yB = yA + (size_t)16 * 2048;
#pragma unroll
  for (int dblk = 0; dblk < 8; ++dblk) {
    unsigned loA = pack2(accA[dblk][0] * invA, accA[dblk][1] * invA);
    unsigned hiA = pack2(accA[dblk][2] * invA, accA[dblk][3] * invA);
    *(uint2*)(yA + 16 * dblk + 4 * lq) = make_uint2(loA, hiA);
    unsigned loB = pack2(accB[dblk][0] * invB, accB[dblk][1] * invB);
    unsigned hiB = pack2(accB[dblk][2] * invB, accB[dblk][3] * invB);
    *(uint2*)(yB + 16 * dblk + 4 * lq) = make_uint2(loB, hiB);
  }
}

// --------------------------------- launch ----------------------------------
extern "C" void kernel_launch(void* const* d_in, const int* in_sizes, int n_in,
                              void* d_out, int out_size, void* d_ws, size_t ws_size,
                              hipStream_t stream) {
  const float* x    = (const float*)d_in[0];
  const float* cosb = (const float*)d_in[1];
  const float* sinb = (const float*)d_in[2];
  const float* wq   = (const float*)d_in[3];
  const float* wk   = (const float*)d_in[4];
  const float* wv   = (const float*)d_in[5];
  const float* wo   = (const float*)d_in[6];
  float* out = (float*)d_out;

  char* ws = (char*)d_ws;
  size_t off = 0;
  auto alloc = [&](size_t bytes) {
    char* p = ws + off; off += (bytes + 255) & ~(size_t)255; return p;
  };
  bf16* xb  = (bf16*)alloc(4096ull * 2048 * 2);
  bf16* wqT = (bf16*)alloc(2048ull * 2048 * 2);
  bf16* wkT = (bf16*)alloc(512ull  * 2048 * 2);
  bf16* wvT = (bf16*)alloc(512ull  * 2048 * 2);
  bf16* woT = (bf16*)alloc(2048ull * 2048 * 2);
  bf16* qkv = (bf16*)alloc(4096ull * 3072 * 2);
  bf16* q_r = (bf16*)alloc(4096ull * 2048 * 2);
  bf16* k_r = (bf16*)alloc(4096ull * 512  * 2);
  bf16* v_t = (bf16*)alloc(4096ull * 512  * 2);
  bf16* y   = xb;                                  // xb dead after gemm_qkv

  k_cvt_bf16<<<(4096 * 2048 / 4) / 256, 256, 0, stream>>>(x, xb);
  k_transpose_cvt<<<dim3(64, 64), 256, 0, stream>>>(wq, wqT, 2048, 2048);
  k_transpose_cvt<<<dim3(16, 64), 256, 0, stream>>>(wk, wkT, 2048, 512);
  k_transpose_cvt<<<dim3(16, 64), 256, 0, stream>>>(wv, wvT, 2048, 512);
  k_transpose_cvt<<<dim3(64, 64), 256, 0, stream>>>(wo, woT, 2048, 2048);
  // qkv = x @ [wq|wk|wv]: BN=256 col-blocks 0-7=wq, 8-9=wk, 10-11=wv
  k_gemm32<256, true><<<dim3(12, 16), 512, 0, stream>>>(xb, wqT, wkT, wvT, 8, 10,
                                                        qkv, 2048, 3072);
  k_rope<<<24576, 256, 0, stream>>>(qkv, cosb, sinb, q_r, k_r, v_t);
  k_attn<<<512, 256, 0, stream>>>(q_r, k_r, v_t, y);
  // out = y @ wo : BM=128 x BN=256 -> grid 8x32 = 256 blocks (full machine)
  k_gemm32<128, false><<<dim3(8, 32), 512, 0, stream>>>(y, woT, woT, woT, 100, 200,
                                                        out, 2048, 2048);
}

// Round 11
// 346.512 us; speedup vs baseline: 1.0993x; 1.0522x over previous
//
#include <hip/hip_runtime.h>
#include <hip/hip_bf16.h>

// ---------------------------------------------------------------------------
// CausalSelfAttention (B=2,T=2048,C=2048,H=16,KVH=4,HD=128) on gfx950.
// cvt(x) ; transpose+cvt(w*) ; ring-GEMM(256)->qkv ; rope+rms (coalesced V) ;
// V-transpose ; flash-attn (swapped-QK^T) ; m97-GEMM(128)->out.
// ---------------------------------------------------------------------------

using bf16 = __bf16;
typedef __bf16 bf16x8 __attribute__((ext_vector_type(8)));
typedef __bf16 bf16x4 __attribute__((ext_vector_type(4)));
typedef float  f32x4  __attribute__((ext_vector_type(4)));

__device__ __forceinline__ void gload_lds16(const void* g, void* l) {
  __builtin_amdgcn_global_load_lds(
      (const __attribute__((address_space(1))) unsigned int*)g,
      (__attribute__((address_space(3))) unsigned int*)l, 16, 0, 0);
}

__device__ __forceinline__ unsigned pack2(float a, float b) {
  unsigned short ua = __builtin_bit_cast(unsigned short, (bf16)a);
  unsigned short ub = __builtin_bit_cast(unsigned short, (bf16)b);
  return ((unsigned)ub << 16) | ua;
}

#define SBAR() do { __builtin_amdgcn_s_barrier(); \
                    __builtin_amdgcn_sched_barrier(0); } while (0)
#define VMCNT(n) asm volatile("s_waitcnt vmcnt(" #n ")" ::: "memory")

// --------------------------- elementwise convert ---------------------------
__global__ __launch_bounds__(256) void k_cvt_bf16(const float* __restrict__ src,
                                                  bf16* __restrict__ dst) {
  const int i = blockIdx.x * 256 + threadIdx.x;
  f32x4 v = ((const f32x4*)src)[i];
  bf16x4 o;
  o[0] = (bf16)v[0]; o[1] = (bf16)v[1]; o[2] = (bf16)v[2]; o[3] = (bf16)v[3];
  ((bf16x4*)dst)[i] = o;
}

// ----------------------- transpose + convert (weights) ---------------------
__global__ __launch_bounds__(256) void k_transpose_cvt(const float* __restrict__ src,
                                                       bf16* __restrict__ dst,
                                                       int R, int C) {
  __shared__ float tile[32][33];
  const int c0 = blockIdx.x * 32, r0 = blockIdx.y * 32;
  const int tx = threadIdx.x & 31, ty = threadIdx.x >> 5;
#pragma unroll
  for (int j = 0; j < 32; j += 8)
    tile[ty + j][tx] = src[(size_t)(r0 + ty + j) * C + c0 + tx];
  __syncthreads();
#pragma unroll
  for (int j = 0; j < 32; j += 8)
    dst[(size_t)(c0 + ty + j) * R + r0 + tx] = (bf16)tile[tx][ty + j];
}

// ----------------------- V transpose (t,d) -> (d,t), bf16 ------------------
__global__ __launch_bounds__(256) void k_vtrans(const bf16* __restrict__ src,
                                                bf16* __restrict__ dst) {
  __shared__ bf16 tile[32][33];
  const int bkv = blockIdx.z;
  const int d0 = blockIdx.x * 32, t0 = blockIdx.y * 32;
  const int tx = threadIdx.x & 31, ty = threadIdx.x >> 5;
  const bf16* s = src + (size_t)bkv * 2048 * 128;
  bf16* d = dst + (size_t)bkv * 128 * 2048;
#pragma unroll
  for (int j = 0; j < 32; j += 8)
    tile[ty + j][tx] = s[(size_t)(t0 + ty + j) * 128 + d0 + tx];
  __syncthreads();
#pragma unroll
  for (int j = 0; j < 32; j += 8)
    d[(size_t)(d0 + ty + j) * 2048 + t0 + tx] = tile[tx][ty + j];
}

// -------------------- ring-buffer GEMM (qkv), BK=32, 4-deep ----------------
template <int BM, bool OUT_BF16>
__global__ __launch_bounds__(512, 1) void k_gemm32(
    const bf16* __restrict__ A,
    const bf16* __restrict__ B0, const bf16* __restrict__ B1,
    const bf16* __restrict__ B2, int nb1, int nb2,
    void* __restrict__ Cout, int K, int Ntot) {
  constexpr int MR  = BM / 32;
  constexpr int ACH = BM / 128;
  __shared__ __align__(16) bf16 As[4][BM * 32];
  __shared__ __align__(16) bf16 Bs[4][256 * 32];
  const int nb = blockIdx.x, mb = blockIdx.y;
  const bf16* Bt; int nloc;
  if (nb < nb1)      { Bt = B0; nloc = nb; }
  else if (nb < nb2) { Bt = B1; nloc = nb - nb1; }
  else               { Bt = B2; nloc = nb - nb2; }
  const int tid = threadIdx.x;
  const int w = tid >> 6, lane = tid & 63;
  const int wm = w >> 2, wn = w & 3;
  const int l16 = lane & 15, lq = lane >> 4;
  const int sr4 = lane >> 2, sc4 = lane & 3;
  const bf16* Ag = A  + (size_t)mb * BM * K;
  const bf16* Bg = Bt + (size_t)nloc * 256 * K;

  f32x4 acc[MR][4] = {};

  auto stage = [&](int t) {
    const int buf = t & 3;
    const int k0 = t * 32;
#pragma unroll
    for (int i = 0; i < 2; ++i) {
      const int r = i * 128 + w * 16 + sr4;
      const int cg = sc4 ^ ((r >> 1) & 3);
      gload_lds16(Bg + (size_t)r * K + k0 + cg * 8,
                  &Bs[buf][(i * 128 + w * 16) * 32]);
    }
#pragma unroll
    for (int i = 0; i < ACH; ++i) {
      const int r = i * 128 + w * 16 + sr4;
      const int cg = sc4 ^ ((r >> 1) & 3);
      gload_lds16(Ag + (size_t)r * K + k0 + cg * 8,
                  &As[buf][(i * 128 + w * 16) * 32]);
    }
  };

  const int NT = K / 32;
  stage(0); stage(1); stage(2);
  if (BM == 256) VMCNT(8); else VMCNT(6);
  SBAR();

  for (int t = 0; t < NT; ++t) {
    const int buf = t & 3;
    if (t + 3 < NT) stage(t + 3);
    const int rem = NT - 1 - t;
    if (BM == 256) {
      if (rem >= 3)      VMCNT(12);
      else if (rem == 2) VMCNT(8);
      else if (rem == 1) VMCNT(4);
      else               VMCNT(0);
    } else {
      if (rem >= 3)      VMCNT(9);
      else if (rem == 2) VMCNT(6);
      else if (rem == 1) VMCNT(3);
      else               VMCNT(0);
    }
    SBAR();
    bf16x8 bfr[4], af[MR];
#pragma unroll
    for (int j = 0; j < 4; ++j) {
      const int rb = wn * 64 + j * 16 + l16;
      bfr[j] = *(const bf16x8*)((const char*)&Bs[buf][0] + rb * 64 +
                                ((lq ^ ((rb >> 1) & 3)) << 4));
    }
#pragma unroll
    for (int i = 0; i < MR; ++i) {
      const int ra = wm * (BM / 2) + i * 16 + l16;
      af[i] = *(const bf16x8*)((const char*)&As[buf][0] + ra * 64 +
                               ((lq ^ ((ra >> 1) & 3)) << 4));
    }
    __builtin_amdgcn_s_setprio(1);
#pragma unroll
    for (int i = 0; i < MR; ++i)
#pragma unroll
      for (int j = 0; j < 4; ++j)
        acc[i][j] = __builtin_amdgcn_mfma_f32_16x16x32_bf16(af[i], bfr[j],
                                                            acc[i][j], 0, 0, 0);
    __builtin_amdgcn_s_setprio(0);
    SBAR();
  }

#pragma unroll
  for (int i = 0; i < MR; ++i)
#pragma unroll
    for (int j = 0; j < 4; ++j)
#pragma unroll
      for (int e = 0; e < 4; ++e) {
        const size_t row = (size_t)mb * BM + wm * (BM / 2) + i * 16 + lq * 4 + e;
        const size_t col = (size_t)nb * 256 + wn * 64 + j * 16 + l16;
        if (OUT_BF16) ((bf16*)Cout)[row * Ntot + col] = (bf16)acc[i][j][e];
        else          ((float*)Cout)[row * Ntot + col] = acc[i][j][e];
      }
}

// ------------- m97-style 128^2 GEMM (out-proj; 32KB LDS, multi-blk/CU) -----
template <bool OUT_BF16>
__global__ __launch_bounds__(256) void k_gemm(
    const bf16* __restrict__ A,
    const bf16* __restrict__ B0, const bf16* __restrict__ B1,
    const bf16* __restrict__ B2, int nb1, int nb2,
    void* __restrict__ Cout, int K, int Ntot) {
  __shared__ __align__(16) bf16 As[128 * 64];
  __shared__ __align__(16) bf16 Bs[128 * 64];
  const int nb = blockIdx.x, mb = blockIdx.y;
  const bf16* Bt; int nloc;
  if (nb < nb1)      { Bt = B0; nloc = nb; }
  else if (nb < nb2) { Bt = B1; nloc = nb - nb1; }
  else               { Bt = B2; nloc = nb - nb2; }
  const int tid = threadIdx.x;
  const int w = tid >> 6, lane = tid & 63;
  const int wm = w >> 1, wn = w & 1;
  const int sr = lane >> 3, sc = lane & 7;
  const int l16 = lane & 15, lq = lane >> 4;
  f32x4 acc[4][4] = {};
  const bf16* Ab = A  + (size_t)(mb * 128) * K;
  const bf16* Bb = Bt + (size_t)(nloc * 128) * K;
  for (int k0 = 0; k0 < K; k0 += 64) {
#pragma unroll
    for (int it = 0; it < 4; ++it) {
      const int r  = w * 32 + it * 8 + sr;
      const int cs = (sc ^ (r & 7)) << 3;
      gload_lds16(Ab + (size_t)r * K + k0 + cs, &As[(w * 32 + it * 8) * 64]);
      gload_lds16(Bb + (size_t)r * K + k0 + cs, &Bs[(w * 32 + it * 8) * 64]);
    }
    __syncthreads();
#pragma unroll
    for (int kc = 0; kc < 2; ++kc) {
      bf16x8 af[4], bfr[4];
#pragma unroll
      for (int i = 0; i < 4; ++i) {
        const int ra = wm * 64 + i * 16 + l16;
        af[i]  = *(const bf16x8*)((const char*)As + ra * 128 +
                                  ((kc * 64 + lq * 16) ^ ((ra & 7) << 4)));
        const int rb = wn * 64 + i * 16 + l16;
        bfr[i] = *(const bf16x8*)((const char*)Bs + rb * 128 +
                                  ((kc * 64 + lq * 16) ^ ((rb & 7) << 4)));
      }
#pragma unroll
      for (int i = 0; i < 4; ++i)
#pragma unroll
        for (int j = 0; j < 4; ++j)
          acc[i][j] = __builtin_amdgcn_mfma_f32_16x16x32_bf16(af[i], bfr[j],
                                                              acc[i][j], 0, 0, 0);
    }
    __syncthreads();
  }
#pragma unroll
  for (int i = 0; i < 4; ++i)
#pragma unroll
    for (int j = 0; j < 4; ++j)
#pragma unroll
      for (int e = 0; e < 4; ++e) {
        const size_t row = (size_t)mb * 128 + wm * 64 + i * 16 + lq * 4 + e;
        const size_t col = (size_t)nb * 128 + wn * 64 + j * 16 + l16;
        if (OUT_BF16) ((bf16*)Cout)[row * Ntot + col] = (bf16)acc[i][j][e];
        else          ((float*)Cout)[row * Ntot + col] = acc[i][j][e];
      }
}

// ----------------------------- RoPE + RMSnorm ------------------------------
// heads 0..15: q ; 16..19: k ; 20..23: v -> CONTIGUOUS copy (v_r, (b,kv,t,d))
__global__ __launch_bounds__(256) void k_rope(
    const bf16* __restrict__ qkv, const float* __restrict__ cosb,
    const float* __restrict__ sinb, bf16* __restrict__ q_r,
    bf16* __restrict__ k_r, bf16* __restrict__ v_r) {
  const int wid  = blockIdx.x * 4 + (threadIdx.x >> 6);
  const int lane = threadIdx.x & 63;
  const int head = wid % 24;
  const int bt   = wid / 24;
  const int b = bt >> 11, t = bt & 2047;
  const bf16* base = qkv + (size_t)bt * 3072;
  if (head >= 20) {
    const int kv = head - 20;
    const size_t o = ((size_t)(b * 4 + kv) * 2048 + t) * 128;
    v_r[o + lane]      = base[2560 + kv * 128 + lane];
    v_r[o + 64 + lane] = base[2560 + kv * 128 + 64 + lane];
    return;
  }
  const int col = (head < 16) ? head * 128 : 2048 + (head - 16) * 128;
  const float x1 = (float)base[col + lane];
  const float x2 = (float)base[col + 64 + lane];
  const float c = cosb[t * 64 + lane], s = sinb[t * 64 + lane];
  const float o1 = x1 * c + x2 * s;
  const float o2 = x2 * c - x1 * s;
  float ss = o1 * o1 + o2 * o2;
#pragma unroll
  for (int off = 32; off >= 1; off >>= 1) ss += __shfl_xor(ss, off);
  float r = rsqrtf(ss * (1.0f / 128.0f) + 1e-5f);
  if (head < 16) {
    r *= 0.08838834764831845f;
    const size_t o = ((size_t)(b * 16 + head) * 2048 + t) * 128;
    q_r[o + lane]      = (bf16)(o1 * r);
    q_r[o + 64 + lane] = (bf16)(o2 * r);
  } else {
    const int kv = head - 16;
    const size_t o = ((size_t)(b * 4 + kv) * 2048 + t) * 128;
    k_r[o + lane]      = (bf16)(o1 * r);
    k_r[o + 64 + lane] = (bf16)(o2 * r);
  }
}

// ------------------------------ flash attention ----------------------------
// (unchanged, verified)
__global__ __launch_bounds__(256, 2) void k_attn(
    const bf16* __restrict__ q_r, const bf16* __restrict__ k_r,
    const bf16* __restrict__ v_t, bf16* __restrict__ y) {
  __shared__ __align__(16) bf16 Ks[2][64 * 128];
  __shared__ __align__(16) bf16 Vt[2][128 * 64];
  const int blkid = blockIdx.x;
  const int bh = (blkid & 7) * 4 + ((blkid >> 3) & 3);
  const int g  = blkid >> 5;
  const int qb = (blkid < 256) ? (15 - g) : (g - 8);
  const int b = bh >> 4, h = bh & 15;
  const int bkv = b * 4 + (h >> 2);
  const int tid = threadIdx.x, w = tid >> 6, lane = tid & 63;
  const int l16 = lane & 15, lq = lane >> 4;
  const int swz = (l16 & 7) << 4;
  const int q0 = qb * 128, t0A = q0 + w * 32;
  const int nt = 2 * qb + 2;
  const bf16* kb = k_r + (size_t)bkv * (2048 * 128);
  const bf16* vb = v_t + (size_t)bkv * (128 * 2048);

  bf16x8 qfA[4], qfB[4];
  const bf16* qbase = q_r + ((size_t)bh * 2048 + t0A + l16) * 128;
#pragma unroll
  for (int kc = 0; kc < 4; ++kc) {
    qfA[kc] = *(const bf16x8*)(qbase + 32 * kc + 8 * lq);
    qfB[kc] = *(const bf16x8*)(qbase + 16 * 128 + 32 * kc + 8 * lq);
  }

  f32x4 accA[8] = {}, accB[8] = {};
  float mA = -1e29f, mB = -1e29f, lA = 0.f, lB = 0.f;

  auto stage = [&](int buf, int s0n) {
#pragma unroll
    for (int it = 0; it < 4; ++it) {
      const int rK = w * 16 + it * 4 + (lane >> 4);
      gload_lds16(kb + (size_t)(s0n + rK) * 128 + (((lane & 15) ^ (rK & 7)) << 3),
                  &Ks[buf][(w * 16 + it * 4) * 128]);
      const int rV = w * 32 + it * 8 + (lane >> 3);
      gload_lds16(vb + (size_t)rV * 2048 + s0n + (((lane & 7) ^ (rV & 7)) << 3),
                  &Vt[buf][(w * 32 + it * 8) * 64]);
    }
  };

  stage(0, 0);
  asm volatile("s_waitcnt vmcnt(0)" ::: "memory");
  __syncthreads();

  for (int t = 0; t < nt; ++t) {
    if (t + 1 < nt) stage((t + 1) & 1, (t + 1) * 64);
    const int s0 = t * 64;
    const int buf = t & 1;
    if (s0 <= t0A + 31) {
      f32x4 stA[4] = {}, stB[4] = {};
#pragma unroll
      for (int kc = 0; kc < 4; ++kc)
#pragma unroll
        for (int n = 0; n < 4; ++n) {
          const int rk = 16 * n + l16;
          const bf16x8 kf = *(const bf16x8*)((const char*)&Ks[buf][0] +
                             rk * 256 + ((64 * kc + 16 * lq) ^ swz));
          stA[n] = __builtin_amdgcn_mfma_f32_16x16x32_bf16(kf, qfA[kc], stA[n], 0, 0, 0);
          stB[n] = __builtin_amdgcn_mfma_f32_16x16x32_bf16(kf, qfB[kc], stB[n], 0, 0, 0);
        }
      const int qgA = t0A + l16, qgB = qgA + 16;
      if (s0 + 63 > t0A) {
#pragma unroll
        for (int n = 0; n < 4; ++n)
#pragma unroll
          for (int e = 0; e < 4; ++e) {
            const int kvg = s0 + 16 * n + 4 * lq + e;
            if (kvg > qgA) stA[n][e] = -1e30f;
            if (kvg > qgB) stB[n][e] = -1e30f;
          }
      }
      float mxA = -1e30f, mxB = -1e30f;
#pragma unroll
      for (int n = 0; n < 4; ++n)
#pragma unroll
        for (int e = 0; e < 4; ++e) {
          mxA = fmaxf(mxA, stA[n][e]);
          mxB = fmaxf(mxB, stB[n][e]);
        }
      mxA = fmaxf(mxA, __shfl_xor(mxA, 16)); mxA = fmaxf(mxA, __shfl_xor(mxA, 32));
      mxB = fmaxf(mxB, __shfl_xor(mxB, 16)); mxB = fmaxf(mxB, __shfl_xor(mxB, 32));
      const bool small = (mxA <= mA + 8.f) && (mxB <= mB + 8.f);
      if (!__all(small)) {
        const float mnA = fmaxf(mA, mxA), mnB = fmaxf(mB, mxB);
        const float scA = __expf(mA - mnA), scB = __expf(mB - mnB);
        mA = mnA; mB = mnB; lA *= scA; lB *= scB;
#pragma unroll
        for (int d2 = 0; d2 < 8; ++d2) { accA[d2] *= scA; accB[d2] *= scB; }
      }
      float rsA = 0.f, rsB = 0.f;
#pragma unroll
      for (int n = 0; n < 4; ++n)
#pragma unroll
        for (int e = 0; e < 4; ++e) {
          stA[n][e] = __expf(stA[n][e] - mA); rsA += stA[n][e];
          stB[n][e] = __expf(stB[n][e] - mB); rsB += stB[n][e];
        }
      rsA += __shfl_xor(rsA, 16); rsA += __shfl_xor(rsA, 32); lA += rsA;
      rsB += __shfl_xor(rsB, 16); rsB += __shfl_xor(rsB, 32); lB += rsB;
      unsigned pA2[8], pB2[8];
#pragma unroll
      for (int n = 0; n < 4; ++n) {
        pA2[n * 2 + 0] = pack2(stA[n][0], stA[n][1]);
        pA2[n * 2 + 1] = pack2(stA[n][2], stA[n][3]);
        pB2[n * 2 + 0] = pack2(stB[n][0], stB[n][1]);
        pB2[n * 2 + 1] = pack2(stB[n][2], stB[n][3]);
      }
      const int src0 = l16 | ((((lq & 1) << 1) | 0) << 4);
      const int src1 = l16 | ((((lq & 1) << 1) | 1) << 4);
      const bool selhi = (lq & 2);
#pragma unroll
      for (int c = 0; c < 2; ++c) {
        union { unsigned u[4]; bf16x8 v; } wA, wB;
        {
          unsigned a0 = __shfl((int)pA2[(2*c)*2+0], src0), b0 = __shfl((int)pA2[(2*c+1)*2+0], src0);
          unsigned a1 = __shfl((int)pA2[(2*c)*2+1], src0), b1 = __shfl((int)pA2[(2*c+1)*2+1], src0);
          unsigned a2 = __shfl((int)pA2[(2*c)*2+0], src1), b2 = __shfl((int)pA2[(2*c+1)*2+0], src1);
          unsigned a3 = __shfl((int)pA2[(2*c)*2+1], src1), b3 = __shfl((int)pA2[(2*c+1)*2+1], src1);
          wA.u[0] = selhi ? b0 : a0; wA.u[1] = selhi ? b1 : a1;
          wA.u[2] = selhi ? b2 : a2; wA.u[3] = selhi ? b3 : a3;
        }
        {
          unsigned a0 = __shfl((int)pB2[(2*c)*2+0], src0), b0 = __shfl((int)pB2[(2*c+1)*2+0], src0);
          unsigned a1 = __shfl((int)pB2[(2*c)*2+1], src0), b1 = __shfl((int)pB2[(2*c+1)*2+1], src0);
          unsigned a2 = __shfl((int)pB2[(2*c)*2+0], src1), b2 = __shfl((int)pB2[(2*c+1)*2+0], src1);
          unsigned a3 = __shfl((int)pB2[(2*c)*2+1], src1), b3 = __shfl((int)pB2[(2*c+1)*2+1], src1);
          wB.u[0] = selhi ? b0 : a0; wB.u[1] = selhi ? b1 : a1;
          wB.u[2] = selhi ? b2 : a2; wB.u[3] = selhi ? b3 : a3;
        }
#pragma unroll
        for (int dblk = 0; dblk < 8; ++dblk) {
          const int rv = 16 * dblk + l16;
          const bf16x8 vf = *(const bf16x8*)((const char*)&Vt[buf][0] +
                             rv * 128 + ((64 * c + 16 * lq) ^ swz));
          accA[dblk] = __builtin_amdgcn_mfma_f32_16x16x32_bf16(vf, wA.v, accA[dblk], 0, 0, 0);
          accB[dblk] = __builtin_amdgcn_mfma_f32_16x16x32_bf16(vf, wB.v, accB[dblk], 0, 0, 0);
        }
      }
    }
    asm volatile("s_waitcnt vmcnt(0)" ::: "memory");
    __syncthreads();
  }

  const float invA = 1.f / lA, invB = 1.f / lB;
  bf16* yA = y + (((size_t)b * 2048 + t0A + l16) * 16 + h) * 128;
  bf16* yB = yA + (size_t)16 * 2048;
#pragma unroll
  for (int dblk = 0; dblk < 8; ++dblk) {
    unsigned loA = pack2(accA[dblk][0] * invA, accA[dblk][1] * invA);
    unsigned hiA = pack2(accA[dblk][2] * invA, accA[dblk][3] * invA);
    *(uint2*)(yA + 16 * dblk + 4 * lq) = make_uint2(loA, hiA);
    unsigned loB = pack2(accB[dblk][0] * invB, accB[dblk][1] * invB);
    unsigned hiB = pack2(accB[dblk][2] * invB, accB[dblk][3] * invB);
    *(uint2*)(yB + 16 * dblk + 4 * lq) = make_uint2(loB, hiB);
  }
}

// --------------------------------- launch ----------------------------------
extern "C" void kernel_launch(void* const* d_in, const int* in_sizes, int n_in,
                              void* d_out, int out_size, void* d_ws, size_t ws_size,
                              hipStream_t stream) {
  const float* x    = (const float*)d_in[0];
  const float* cosb = (const float*)d_in[1];
  const float* sinb = (const float*)d_in[2];
  const float* wq   = (const float*)d_in[3];
  const float* wk   = (const float*)d_in[4];
  const float* wv   = (const float*)d_in[5];
  const float* wo   = (const float*)d_in[6];
  float* out = (float*)d_out;

  char* ws = (char*)d_ws;
  size_t off = 0;
  auto alloc = [&](size_t bytes) {
    char* p = ws + off; off += (bytes + 255) & ~(size_t)255; return p;
  };
  bf16* xb  = (bf16*)alloc(4096ull * 2048 * 2);
  bf16* wqT = (bf16*)alloc(2048ull * 2048 * 2);
  bf16* wkT = (bf16*)alloc(512ull  * 2048 * 2);
  bf16* wvT = (bf16*)alloc(512ull  * 2048 * 2);
  bf16* woT = (bf16*)alloc(2048ull * 2048 * 2);
  bf16* qkv = (bf16*)alloc(4096ull * 3072 * 2);
  bf16* q_r = (bf16*)alloc(4096ull * 2048 * 2);
  bf16* k_r = (bf16*)alloc(4096ull * 512  * 2);
  bf16* v_r = (bf16*)alloc(4096ull * 512  * 2);
  bf16* v_t = (bf16*)alloc(4096ull * 512  * 2);
  bf16* y   = xb;                                  // xb dead after gemm_qkv

  k_cvt_bf16<<<(4096 * 2048 / 4) / 256, 256, 0, stream>>>(x, xb);
  k_transpose_cvt<<<dim3(64, 64), 256, 0, stream>>>(wq, wqT, 2048, 2048);
  k_transpose_cvt<<<dim3(16, 64), 256, 0, stream>>>(wk, wkT, 2048, 512);
  k_transpose_cvt<<<dim3(16, 64), 256, 0, stream>>>(wv, wvT, 2048, 512);
  k_transpose_cvt<<<dim3(64, 64), 256, 0, stream>>>(wo, woT, 2048, 2048);
  // qkv = x @ [wq|wk|wv]: BN=256 col-blocks 0-7=wq, 8-9=wk, 10-11=wv
  k_gemm32<256, true><<<dim3(12, 16), 512, 0, stream>>>(xb, wqT, wkT, wvT, 8, 10,
                                                        qkv, 2048, 3072);
  k_rope<<<24576, 256, 0, stream>>>(qkv, cosb, sinb, q_r, k_r, v_r);
  k_vtrans<<<dim3(4, 64, 8), 256, 0, stream>>>(v_r, v_t);
  k_attn<<<512, 256, 0, stream>>>(q_r, k_r, v_t, y);
  // out = y @ wo : m97-style 128^2, grid 16x32 = 512 blocks (2 CU rounds)
  k_gemm<false><<<dim3(16, 32), 256, 0, stream>>>(y, woT, woT, woT, 100, 200,
                                                  out, 2048, 2048);
}